// Round 15
// baseline (265.189 us; speedup 1.0000x reference)
//
#include <hip/hip_runtime.h>
#include <stdint.h>

#define AS1 __attribute__((address_space(1)))
#define AS3 __attribute__((address_space(3)))

typedef short v8s __attribute__((ext_vector_type(8)));
typedef float v4f __attribute__((ext_vector_type(4)));

__device__ __forceinline__ float b2f(unsigned short u) {
  return __uint_as_float(((unsigned int)u) << 16);
}
__device__ __forceinline__ unsigned short f2bu(float f) {
  unsigned int u = __float_as_uint(f);
  u += 0x7fffu + ((u >> 16) & 1u);
  return (unsigned short)(u >> 16);
}

__device__ __forceinline__ void gload16(const void* g, const void* l) {
  __builtin_amdgcn_global_load_lds(
      (const AS1 void*)(uintptr_t)g,
      (AS3 void*)(unsigned)(uintptr_t)l,
      16, 0, 0);
}

#define BAR __builtin_amdgcn_s_barrier()
#define VMC2 asm volatile("s_waitcnt vmcnt(2)" ::: "memory")
#define VMC0 asm volatile("s_waitcnt vmcnt(0)" ::: "memory")

// ---------------------------------------------------------------------------
// All weight transposes in ONE launch. grid (16,16,19), 64x64 tiles.
// ---------------------------------------------------------------------------
__global__ __launch_bounds__(256)
void transpose_all(const float* __restrict__ wq, const float* __restrict__ wk,
                   const float* __restrict__ wv, const float* __restrict__ w1,
                   const float* __restrict__ w2,
                   unsigned short* __restrict__ Wqt,
                   unsigned short* __restrict__ W1t,
                   unsigned short* __restrict__ W2t)
{
  __shared__ float t[64][65];
  const int z = blockIdx.z;
  const float* src;
  unsigned short* dst;
  int ld;
  if (z < 3) {
    src = (z == 0) ? wq : (z == 1) ? wk : wv;
    dst = Wqt + (long long)z * 1048576;
    ld = 1024;
  } else if (z < 11) {
    src = w1 + (long long)(z - 3) * 1048576;
    dst = W1t + (long long)(z - 3) * 1048576;
    ld = 1024;
  } else {
    src = w2 + (long long)(z - 11) * 1048576;
    dst = W2t + (long long)(z - 11) * 1024;
    ld = 8192;
  }
  const int k0 = blockIdx.y * 64, n0 = blockIdx.x * 64;
  const int tr  = threadIdx.x >> 4;
  const int tc4 = (threadIdx.x & 15) * 4;
#pragma unroll
  for (int p = 0; p < 4; ++p) {
    float4 v = *(const float4*)(src + (long long)(k0 + tr + p * 16) * 1024 + n0 + tc4);
    t[tr + p * 16][tc4 + 0] = v.x;
    t[tr + p * 16][tc4 + 1] = v.y;
    t[tr + p * 16][tc4 + 2] = v.z;
    t[tr + p * 16][tc4 + 3] = v.w;
  }
  __syncthreads();
#pragma unroll
  for (int p = 0; p < 4; ++p) {
    const int n = tr + p * 16;
    ushort4 o;
    o.x = f2bu(t[tc4 + 0][n]);
    o.y = f2bu(t[tc4 + 1][n]);
    o.z = f2bu(t[tc4 + 2][n]);
    o.w = f2bu(t[tc4 + 3][n]);
    *(ushort4*)(dst + (long long)(n0 + n) * ld + k0 + tc4) = o;
  }
}

__global__ __launch_bounds__(256)
void cvt_f32_bf16(const float* __restrict__ src, unsigned short* __restrict__ dst, int n)
{
  const int i = (blockIdx.x * 256 + threadIdx.x) * 4;
  if (i >= n) return;
  float4 v = *(const float4*)(src + i);
  ushort4 o;
  o.x = f2bu(v.x); o.y = f2bu(v.y); o.z = f2bu(v.z); o.w = f2bu(v.w);
  *(ushort4*)(dst + i) = o;
}

// ---------------------------------------------------------------------------
// 256x256 bf16 GEMM (R12 configuration — session-best verified).
// 8 waves (2Mx4N), BK=64, 8 phases / 2 K-tiles, single post-MFMA barrier,
// b1-hoist (all B reads at ph1/ph5), VMC2@ph4/ph8 FIFO ledger,
// st_16x32-swizzled subtiled LDS (conflicts=0), source pre-swizzled (rule 21).
// NO XCD swizzle (R14: time-neutral, 2.6x FETCH — reverted).
// EPI 0: bf16 Q/K/V out = acc + bias[col]; out slab = col>>10
// EPI 1: bf16 out = gate * gelu_new(acc + bias[col])  (hs, ld 8192)
// EPI 3: split-K partial: z=0 -> f32 out0, z>0 -> bf16 pbs[z-1]
// ---------------------------------------------------------------------------
template<int MH>
__device__ __forceinline__ void read_a(v8s af[4][2],
    const unsigned short* pa, int wm, int rswz)
{
#pragma unroll
  for (int i = 0; i < 4; ++i)
#pragma unroll
    for (int s = 0; s < 2; ++s)
      af[i][s] = *(const v8s*)(pa + MH*8192 + ((((wm*4 + i)*2 + s) << 9) | rswz));
}

template<int NH>
__device__ __forceinline__ void read_b(v8s bfr[2][2],
    const unsigned short* pb, int wn, int rswz)
{
#pragma unroll
  for (int j = 0; j < 2; ++j)
#pragma unroll
    for (int s = 0; s < 2; ++s)
      bfr[j][s] = *(const v8s*)(pb + NH*8192 + ((((wn*2 + j)*2 + s) << 9) | rswz));
}

template<int MH, int NH>
__device__ __forceinline__ void mfma16(v4f acc[8][4], v8s af[4][2], v8s bfr[2][2])
{
  __builtin_amdgcn_s_setprio(1);
#pragma unroll
  for (int i = 0; i < 4; ++i)
#pragma unroll
    for (int j = 0; j < 2; ++j)
#pragma unroll
      for (int s = 0; s < 2; ++s)
        acc[MH*4+i][NH*2+j] = __builtin_amdgcn_mfma_f32_16x16x32_bf16(
            af[i][s], bfr[j][s], acc[MH*4+i][NH*2+j], 0, 0, 0);
  __builtin_amdgcn_s_setprio(0);
}

#define STAGE(G, LD, LDSBASE, GROW0, KT) do { \
    gload16((G) + (long long)((GROW0) + sRow) * (LD) + (KT) + sCol, \
            (LDSBASE) + w512); \
    gload16((G) + (long long)((GROW0) + 64 + sRow) * (LD) + (KT) + sCol, \
            (LDSBASE) + 4096 + w512); \
  } while (0)

template<int EPI>
__global__ __launch_bounds__(512, 2)
void gemm256(const unsigned short* __restrict__ A, int lda,
             const unsigned short* __restrict__ Bt, int ldb,
             const float* __restrict__ bias,
             void* __restrict__ out0, unsigned short* __restrict__ pbs,
             int kLen, const float* __restrict__ gates)
{
  __shared__ __align__(16) unsigned short lds[65536];   // 128 KiB
  unsigned short* As0 = lds;
  unsigned short* As1 = lds + 16384;
  unsigned short* Bs0 = lds + 32768;
  unsigned short* Bs1 = lds + 49152;

  const int tid  = threadIdx.x;
  const int lane = tid & 63;
  const int w    = tid >> 6;        // 0..7
  const int wm   = w >> 2;          // 0..1
  const int wn   = w & 3;           // 0..3
  const int m0   = blockIdx.y * 256;
  const int n0   = blockIdx.x * 256;
  const int z    = blockIdx.z;
  const int kBase = (EPI == 3) ? z * kLen : 0;

  const int sRow = (w >> 1) * 16 + (lane >> 2);
  const int sCol = (w & 1) * 32 + (((lane & 3) * 8) ^ (((lane >> 5) & 1) << 4));
  const int rr   = lane & 15;
  const int kgrp = lane >> 4;
  const int rswz = (rr * 32 + kgrp * 8) ^ ((rr & 8) << 1);
  const int w512 = w * 512;

  v4f acc[8][4] = {};
  v8s af[4][2], b0[2][2], b1[2][2];

  const int iters = kLen >> 7;   // 2 K-tiles (BK=64) per iteration

  // ---- prologue: buf0 full (8 gloads) + buf1 A-lo (2) ----
  STAGE(A,  lda, As0,        m0,       kBase);
  STAGE(A,  lda, As0 + 8192, m0 + 128, kBase);
  STAGE(Bt, ldb, Bs0,        n0,       kBase);
  STAGE(Bt, ldb, Bs0 + 8192, n0 + 128, kBase);
  STAGE(A,  lda, As1,        m0,       kBase + 64);
  VMC2;   // buf0 landed; buf1-Alo in flight
  BAR;

  for (int it = 0; it < iters; ++it) {
    const bool nl = (it != iters - 1);
    const int k0t = kBase + it * 128;
    const int kT1 = k0t + 64, kT2 = k0t + 128, kT3 = k0t + 192;

    // ph1: q(0,0) buf0 | reads af-lo, b0, b1 | stage Bs1-lo (T+1)
    read_a<0>(af, As0, wm, rswz);
    read_b<0>(b0, Bs0, wn, rswz);
    read_b<1>(b1, Bs0, wn, rswz);
    STAGE(Bt, ldb, Bs1, n0, kT1);
    mfma16<0,0>(acc, af, b0);
    BAR;
    // ph2: q(0,1) | stage Bs1-hi (T+1)
    STAGE(Bt, ldb, Bs1 + 8192, n0 + 128, kT1);
    mfma16<0,1>(acc, af, b1);
    BAR;
    // ph3: q(1,1) | read af-hi | stage As1-hi (T+1)
    read_a<1>(af, As0, wm, rswz);
    STAGE(A, lda, As1 + 8192, m0 + 128, kT1);
    mfma16<1,1>(acc, af, b1);
    BAR;
    // ph4: q(1,0) | stage As0-lo (T+2) | VMC: buf1 landed
    if (nl) STAGE(A, lda, As0, m0, kT2);
    mfma16<1,0>(acc, af, b0);
    if (nl) { VMC2; } else { VMC0; }
    BAR;
    // ph5: q(0,0) buf1 | reads af-lo, b0, b1 | stage Bs0-lo (T+2)
    read_a<0>(af, As1, wm, rswz);
    read_b<0>(b0, Bs1, wn, rswz);
    read_b<1>(b1, Bs1, wn, rswz);
    if (nl) STAGE(Bt, ldb, Bs0, n0, kT2);
    mfma16<0,0>(acc, af, b0);
    BAR;
    // ph6: q(0,1) | stage Bs0-hi (T+2)
    if (nl) STAGE(Bt, ldb, Bs0 + 8192, n0 + 128, kT2);
    mfma16<0,1>(acc, af, b1);
    BAR;
    // ph7: q(1,1) | read af-hi | stage As0-hi (T+2)
    read_a<1>(af, As1, wm, rswz);
    if (nl) STAGE(A, lda, As0 + 8192, m0 + 128, kT2);
    mfma16<1,1>(acc, af, b1);
    BAR;
    // ph8: q(1,0) | stage As1-lo (T+3) | VMC2: buf0(T+2) landed
    if (nl) STAGE(A, lda, As1, m0, kT3);
    mfma16<1,0>(acc, af, b0);
    if (nl) { VMC2; }
    BAR;
  }

  // ---- epilogue ----
  const int lr4 = (lane >> 4) * 4;
  const int lc  = lane & 15;
  float gate = 0.f;
  if (EPI == 1) gate = gates[(m0 >> 10) * 8 + (n0 >> 10)];

#pragma unroll
  for (int mi = 0; mi < 8; ++mi) {
    const int rowb = m0 + (mi >> 2) * 128 + wm * 64 + (mi & 3) * 16 + lr4;
#pragma unroll
    for (int nj = 0; nj < 4; ++nj) {
      const int col = n0 + (nj >> 1) * 128 + wn * 32 + (nj & 1) * 16 + lc;
#pragma unroll
      for (int r = 0; r < 4; ++r) {
        const int row = rowb + r;
        float v = acc[mi][nj][r];
        if (EPI == 0) {
          v += bias[col];
          const int which = col >> 10;
          ((unsigned short*)out0)[(long long)which * 4194304 + (long long)row * 1024 + (col & 1023)] = f2bu(v);
        } else if (EPI == 1) {
          v += bias[col];
          float u = 0.7978845608028654f * (v + 0.044715f * v * v * v);
          u = fminf(fmaxf(u, -15.f), 15.f);
          float e2 = __expf(2.f * u);
          float th = (e2 - 1.f) / (e2 + 1.f);
          ((unsigned short*)out0)[(long long)row * 8192 + col] = f2bu(gate * 0.5f * v * (1.f + th));
        } else {
          if (z == 0) ((float*)out0)[(long long)row * 1024 + col] = v;
          else pbs[(long long)(z - 1) * 4194304 + (long long)row * 1024 + col] = f2bu(v);
        }
      }
    }
  }
}

// ---------------------------------------------------------------------------
// out = out + pb0 + pb1 + pb2 (bf16 partials) + bias2[b][n]
// ---------------------------------------------------------------------------
__global__ __launch_bounds__(256)
void reduce3(float* __restrict__ out, const unsigned short* __restrict__ pb,
             const float* __restrict__ bias2)
{
  const int i = (blockIdx.x * 256 + threadIdx.x) * 4;
  const int b = i >> 20;
  const int n = i & 1023;
  float4 a = *(const float4*)(out + i);
  ushort4 p0 = *(const ushort4*)(pb + i);
  ushort4 p1 = *(const ushort4*)(pb + 4194304 + i);
  ushort4 p2 = *(const ushort4*)(pb + 8388608 + i);
  float4 bb = *(const float4*)(bias2 + b * 1024 + n);
  a.x += b2f(p0.x) + b2f(p1.x) + b2f(p2.x) + bb.x;
  a.y += b2f(p0.y) + b2f(p1.y) + b2f(p2.y) + bb.y;
  a.z += b2f(p0.z) + b2f(p1.z) + b2f(p2.z) + bb.z;
  a.w += b2f(p0.w) + b2f(p1.w) + b2f(p2.w) + bb.w;
  *(float4*)(out + i) = a;
}

// ---------------------------------------------------------------------------
// Per-token cross-head attention
// ---------------------------------------------------------------------------
__global__ __launch_bounds__(256)
void attn_kernel(const unsigned short* __restrict__ Qb,
                 const unsigned short* __restrict__ Kb,
                 const unsigned short* __restrict__ Vb,
                 unsigned short* __restrict__ a)
{
  const int token = blockIdx.x;
  const int b = token >> 10, s = token & 1023;
  __shared__ float Qs[16][65], Ks[16][65], Vs[16][65];
  __shared__ float attn_s[16][17];
  const int t = threadIdx.x;
  const long long base = (long long)token * 1024;

  {
    const int i0 = t * 4;
    const int hh = i0 >> 6, dd = i0 & 63;
    ushort4 qv = *(const ushort4*)(Qb + base + i0);
    ushort4 kv = *(const ushort4*)(Kb + base + i0);
    ushort4 vv = *(const ushort4*)(Vb + base + i0);
    Qs[hh][dd+0]=b2f(qv.x); Qs[hh][dd+1]=b2f(qv.y); Qs[hh][dd+2]=b2f(qv.z); Qs[hh][dd+3]=b2f(qv.w);
    Ks[hh][dd+0]=b2f(kv.x); Ks[hh][dd+1]=b2f(kv.y); Ks[hh][dd+2]=b2f(kv.z); Ks[hh][dd+3]=b2f(kv.w);
    Vs[hh][dd+0]=b2f(vv.x); Vs[hh][dd+1]=b2f(vv.y); Vs[hh][dd+2]=b2f(vv.z); Vs[hh][dd+3]=b2f(vv.w);
  }
  __syncthreads();

  const int q = t >> 4, k = t & 15;
  float sc = 0.f;
#pragma unroll
  for (int d = 0; d < 64; ++d) sc += Qs[q][d] * Ks[k][d];
  sc *= 0.125f;
  float mx = sc;
#pragma unroll
  for (int m = 1; m < 16; m <<= 1) mx = fmaxf(mx, __shfl_xor(mx, m, 64));
  float ex = __expf(sc - mx);
  float sum = ex;
#pragma unroll
  for (int m = 1; m < 16; m <<= 1) sum += __shfl_xor(sum, m, 64);
  attn_s[q][k] = ex / sum;
  __syncthreads();

  const int hd = t & 63;
  const int wv = t >> 6;
#pragma unroll
  for (int r = 0; r < 4; ++r) {
    const int qq = wv * 4 + r;
    float o = 0.f;
#pragma unroll
    for (int kk = 0; kk < 16; ++kk) o += attn_s[qq][kk] * Vs[kk][hd];
    a[(long long)b * 1048576 + (long long)(qq * 64 + (s >> 4)) * 1024 + (s & 15) * 64 + hd] = f2bu(o);
  }
}

// ---------------------------------------------------------------------------
// Partial column sums, vectorized ushort4
// ---------------------------------------------------------------------------
__global__ __launch_bounds__(256)
void col_sum_part(const unsigned short* __restrict__ a, float* __restrict__ part)
{
  const int b = blockIdx.x;
  const int y = blockIdx.y;
  const int d4 = threadIdx.x * 4;
  const unsigned short* p = a + (long long)b * 1048576 + (long long)y * 131072 + d4;
  float s0 = 0.f, s1 = 0.f, s2 = 0.f, s3 = 0.f;
  for (int i = 0; i < 128; ++i) {
    ushort4 v = *(const ushort4*)(p + i * 1024);
    s0 += b2f(v.x); s1 += b2f(v.y); s2 += b2f(v.z); s3 += b2f(v.w);
  }
  float* o = part + (y * 4 + b) * 1024 + d4;
  o[0] = s0; o[1] = s1; o[2] = s2; o[3] = s3;
}

__global__ __launch_bounds__(256)
void gates_bias2(const float* __restrict__ part,
                 const float* __restrict__ Wg,
                 const float* __restrict__ bg,
                 const float* __restrict__ b2,
                 float* __restrict__ gates,
                 float* __restrict__ bias2)
{
  __shared__ float am[4][1024];
  __shared__ float sg[4][8];
  const int t = threadIdx.x;

  for (int i = t; i < 4096; i += 256) {
    const int b = i >> 10, d = i & 1023;
    float s = 0.f;
#pragma unroll
    for (int y = 0; y < 8; ++y) s += part[(y * 4 + b) * 1024 + d];
    am[b][d] = s * (1.f / 1024.f);
  }
  __syncthreads();

  const int pair = t >> 3, subl = t & 7;
  const int b = pair >> 3, e = pair & 7;
  float s = 0.f;
  for (int d = subl * 128; d < subl * 128 + 128; ++d) s += am[b][d] * Wg[d * 8 + e];
#pragma unroll
  for (int m = 1; m < 8; m <<= 1) s += __shfl_xor(s, m, 64);
  if (subl == 0) sg[b][e] = s + bg[e];
  __syncthreads();

  if (t < 4) {
    float mx = -1e30f;
    for (int ee = 0; ee < 8; ++ee) mx = fmaxf(mx, sg[t][ee]);
    float g[8]; float ssum = 0.f;
    for (int ee = 0; ee < 8; ++ee) { g[ee] = __expf(sg[t][ee] - mx); ssum += g[ee]; }
    for (int ee = 0; ee < 8; ++ee) { sg[t][ee] = g[ee] / ssum; gates[t * 8 + ee] = sg[t][ee]; }
  }
  __syncthreads();

  for (int i = t; i < 4096; i += 256) {
    const int bb = i >> 10, n = i & 1023;
    float ss = 0.f;
#pragma unroll
    for (int ee = 0; ee < 8; ++ee) ss += sg[bb][ee] * b2[ee * 1024 + n];
    bias2[i] = ss;
  }
}

// ---------------------------------------------------------------------------
// Host launch
// ---------------------------------------------------------------------------
extern "C" void kernel_launch(void* const* d_in, const int* in_sizes, int n_in,
                              void* d_out, int out_size, void* d_ws, size_t ws_size,
                              hipStream_t stream) {
  const float* x  = (const float*)d_in[0];
  const float* Wq = (const float*)d_in[1];
  const float* bq = (const float*)d_in[2];
  const float* Wk = (const float*)d_in[3];
  const float* bk = (const float*)d_in[4];
  const float* Wv = (const float*)d_in[5];
  const float* bv = (const float*)d_in[6];
  const float* Wg = (const float*)d_in[7];
  const float* bg = (const float*)d_in[8];
  const float* W1 = (const float*)d_in[9];
  const float* b1 = (const float*)d_in[10];
  const float* W2 = (const float*)d_in[11];
  const float* b2 = (const float*)d_in[12];
  float* out = (float*)d_out;

  if (ws_size < (size_t)109300000) return;

  char* ws = (char*)d_ws;
  unsigned short* xb   = (unsigned short*)(ws + 0);
  unsigned short* Wqt  = (unsigned short*)(ws + 8388608);     // [3072][1024]
  unsigned short* Qb   = (unsigned short*)(ws + 14680064);    // Q,K,V [3][4096][1024]
  unsigned short* hs   = (unsigned short*)(ws + 0);           // [4096][8192]
  unsigned short* abuf = (unsigned short*)(ws + 67108864);    // [4096][1024]
  unsigned short* pbs  = (unsigned short*)(ws + 67108864);    // 3x[4096][1024] bf16 (after EPI1)
  unsigned short* W1t  = (unsigned short*)(ws + 75497472);    // [8192][1024]
  unsigned short* W2t  = (unsigned short*)(ws + 92274688);    // [1024][8192]
  float* part  = (float*)(ws + 109051904);
  float* gates = (float*)(ws + 109051904 + 131072);
  float* bias2 = (float*)(ws + 109051904 + 131072 + 512);
  float* bqkv  = (float*)(ws + 109051904 + 131072 + 512 + 16384);

  dim3 tb(256);

  transpose_all<<<dim3(16,16,19), tb, 0, stream>>>(Wq, Wk, Wv, W1, W2, Wqt, W1t, W2t);
  cvt_f32_bf16<<<4096, tb, 0, stream>>>(x, xb, 4194304);
  hipMemcpyAsync(bqkv,        bq, 4096, hipMemcpyDeviceToDevice, stream);
  hipMemcpyAsync(bqkv + 1024, bk, 4096, hipMemcpyDeviceToDevice, stream);
  hipMemcpyAsync(bqkv + 2048, bv, 4096, hipMemcpyDeviceToDevice, stream);

  // QKV: M=4096, N=3072 (flat), K=1024
  gemm256<0><<<dim3(12,16,1), 512, 0, stream>>>(xb, 1024, Wqt, 1024, bqkv,
                                                Qb, nullptr, 1024, nullptr);
  // Attention -> scrambled a
  attn_kernel<<<4096, tb, 0, stream>>>(Qb, Qb + 4194304, Qb + 8388608, abuf);
  // Gating
  col_sum_part<<<dim3(4,8), tb, 0, stream>>>(abuf, part);
  gates_bias2<<<1, tb, 0, stream>>>(part, Wg, bg, b2, gates, bias2);
  // Expert up-proj + gelu + gate: M=4096, N=8192 (flat experts), K=1024
  gemm256<1><<<dim3(32,16,1), 512, 0, stream>>>(abuf, 1024, W1t, 1024, b1,
                                                hs, nullptr, 1024, gates);
  // Final down-proj: M=4096, N=1024, K=8192, split-K 4 (z=0 -> out f32, z>0 -> bf16 partials)
  gemm256<3><<<dim3(4,16,4), 512, 0, stream>>>(hs, 8192, W2t, 8192, nullptr,
                                               out, pbs, 2048, nullptr);
  reduce3<<<4096, tb, 0, stream>>>(out, pbs, bias2);
}

// Round 16
// 263.558 us; speedup vs baseline: 1.0062x; 1.0062x over previous
//
#include <hip/hip_runtime.h>
#include <stdint.h>

#define AS1 __attribute__((address_space(1)))
#define AS3 __attribute__((address_space(3)))

typedef short v8s __attribute__((ext_vector_type(8)));
typedef float v4f __attribute__((ext_vector_type(4)));

__device__ __forceinline__ float b2f(unsigned short u) {
  return __uint_as_float(((unsigned int)u) << 16);
}
__device__ __forceinline__ unsigned short f2bu(float f) {
  unsigned int u = __float_as_uint(f);
  u += 0x7fffu + ((u >> 16) & 1u);
  return (unsigned short)(u >> 16);
}

__device__ __forceinline__ void gload16(const void* g, const void* l) {
  __builtin_amdgcn_global_load_lds(
      (const AS1 void*)(uintptr_t)g,
      (AS3 void*)(unsigned)(uintptr_t)l,
      16, 0, 0);
}

#define BAR __builtin_amdgcn_s_barrier()
#define VMC2 asm volatile("s_waitcnt vmcnt(2)" ::: "memory")
#define VMC0 asm volatile("s_waitcnt vmcnt(0)" ::: "memory")

// ---------------------------------------------------------------------------
// All weight transposes in ONE launch. grid (16,16,19), 64x64 tiles.
// ---------------------------------------------------------------------------
__global__ __launch_bounds__(256)
void transpose_all(const float* __restrict__ wq, const float* __restrict__ wk,
                   const float* __restrict__ wv, const float* __restrict__ w1,
                   const float* __restrict__ w2,
                   unsigned short* __restrict__ Wqt,
                   unsigned short* __restrict__ W1t,
                   unsigned short* __restrict__ W2t)
{
  __shared__ float t[64][65];
  const int z = blockIdx.z;
  const float* src;
  unsigned short* dst;
  int ld;
  if (z < 3) {
    src = (z == 0) ? wq : (z == 1) ? wk : wv;
    dst = Wqt + (long long)z * 1048576;
    ld = 1024;
  } else if (z < 11) {
    src = w1 + (long long)(z - 3) * 1048576;
    dst = W1t + (long long)(z - 3) * 1048576;
    ld = 1024;
  } else {
    src = w2 + (long long)(z - 11) * 1048576;
    dst = W2t + (long long)(z - 11) * 1024;
    ld = 8192;
  }
  const int k0 = blockIdx.y * 64, n0 = blockIdx.x * 64;
  const int tr  = threadIdx.x >> 4;
  const int tc4 = (threadIdx.x & 15) * 4;
#pragma unroll
  for (int p = 0; p < 4; ++p) {
    float4 v = *(const float4*)(src + (long long)(k0 + tr + p * 16) * 1024 + n0 + tc4);
    t[tr + p * 16][tc4 + 0] = v.x;
    t[tr + p * 16][tc4 + 1] = v.y;
    t[tr + p * 16][tc4 + 2] = v.z;
    t[tr + p * 16][tc4 + 3] = v.w;
  }
  __syncthreads();
#pragma unroll
  for (int p = 0; p < 4; ++p) {
    const int n = tr + p * 16;
    ushort4 o;
    o.x = f2bu(t[tc4 + 0][n]);
    o.y = f2bu(t[tc4 + 1][n]);
    o.z = f2bu(t[tc4 + 2][n]);
    o.w = f2bu(t[tc4 + 3][n]);
    *(ushort4*)(dst + (long long)(n0 + n) * ld + k0 + tc4) = o;
  }
}

__global__ __launch_bounds__(256)
void cvt_f32_bf16(const float* __restrict__ src, unsigned short* __restrict__ dst, int n)
{
  const int i = (blockIdx.x * 256 + threadIdx.x) * 4;
  if (i >= n) return;
  float4 v = *(const float4*)(src + i);
  ushort4 o;
  o.x = f2bu(v.x); o.y = f2bu(v.y); o.z = f2bu(v.z); o.w = f2bu(v.w);
  *(ushort4*)(dst + i) = o;
}

// ---------------------------------------------------------------------------
// 256x256 bf16 GEMM (R12 structure) with COMPILE-TIME leading dims LDA/LDB:
// all staging address math strength-reduces to induction variables (+256B/it)
// instead of per-phase v_mul_lo+64b-add chains on runtime lda (VALUBusy 43%
// diagnosis).  Schedule/layout/registers otherwise identical to R12:
// 8 waves (2Mx4N), BK=64, 8 phases / 2 K-tiles, single post-MFMA barrier,
// b1-hoist, VMC2@ph4/ph8 FIFO ledger, st_16x32-swizzled subtiled LDS.
// EPI 0: bf16 Q/K/V out = acc + bias[col]; out slab = col>>10
// EPI 1: bf16 out = gate * gelu_new(acc + bias[col])  (hs, ld 8192)
// EPI 3: split-K partial: z=0 -> f32 out0, z>0 -> bf16 pbs[z-1]
// ---------------------------------------------------------------------------
template<int MH>
__device__ __forceinline__ void read_a(v8s af[4][2],
    const unsigned short* pa, int wm, int rswz)
{
#pragma unroll
  for (int i = 0; i < 4; ++i)
#pragma unroll
    for (int s = 0; s < 2; ++s)
      af[i][s] = *(const v8s*)(pa + MH*8192 + ((((wm*4 + i)*2 + s) << 9) | rswz));
}

template<int NH>
__device__ __forceinline__ void read_b(v8s bfr[2][2],
    const unsigned short* pb, int wn, int rswz)
{
#pragma unroll
  for (int j = 0; j < 2; ++j)
#pragma unroll
    for (int s = 0; s < 2; ++s)
      bfr[j][s] = *(const v8s*)(pb + NH*8192 + ((((wn*2 + j)*2 + s) << 9) | rswz));
}

template<int MH, int NH>
__device__ __forceinline__ void mfma16(v4f acc[8][4], v8s af[4][2], v8s bfr[2][2])
{
  __builtin_amdgcn_s_setprio(1);
#pragma unroll
  for (int i = 0; i < 4; ++i)
#pragma unroll
    for (int j = 0; j < 2; ++j)
#pragma unroll
      for (int s = 0; s < 2; ++s)
        acc[MH*4+i][NH*2+j] = __builtin_amdgcn_mfma_f32_16x16x32_bf16(
            af[i][s], bfr[j][s], acc[MH*4+i][NH*2+j], 0, 0, 0);
  __builtin_amdgcn_s_setprio(0);
}

#define STAGE(G, LD, LDSBASE, GROW0, KT) do { \
    gload16((G) + (long long)((GROW0) + sRow) * (LD) + (KT) + sCol, \
            (LDSBASE) + w512); \
    gload16((G) + (long long)((GROW0) + 64 + sRow) * (LD) + (KT) + sCol, \
            (LDSBASE) + 4096 + w512); \
  } while (0)

template<int EPI, int LDA, int LDB>
__global__ __launch_bounds__(512, 2)
void gemm256(const unsigned short* __restrict__ A,
             const unsigned short* __restrict__ Bt,
             const float* __restrict__ bias,
             void* __restrict__ out0, unsigned short* __restrict__ pbs,
             int kLen, const float* __restrict__ gates)
{
  __shared__ __align__(16) unsigned short lds[65536];   // 128 KiB
  unsigned short* As0 = lds;
  unsigned short* As1 = lds + 16384;
  unsigned short* Bs0 = lds + 32768;
  unsigned short* Bs1 = lds + 49152;

  const int tid  = threadIdx.x;
  const int lane = tid & 63;
  const int w    = tid >> 6;        // 0..7
  const int wm   = w >> 2;          // 0..1
  const int wn   = w & 3;           // 0..3
  const int m0   = blockIdx.y * 256;
  const int n0   = blockIdx.x * 256;
  const int z    = blockIdx.z;
  const int kBase = (EPI == 3) ? z * kLen : 0;

  const int sRow = (w >> 1) * 16 + (lane >> 2);
  const int sCol = (w & 1) * 32 + (((lane & 3) * 8) ^ (((lane >> 5) & 1) << 4));
  const int rr   = lane & 15;
  const int kgrp = lane >> 4;
  const int rswz = (rr * 32 + kgrp * 8) ^ ((rr & 8) << 1);
  const int w512 = w * 512;

  v4f acc[8][4] = {};
  v8s af[4][2], b0[2][2], b1[2][2];

  const int iters = kLen >> 7;   // 2 K-tiles (BK=64) per iteration

  // ---- prologue: buf0 full (8 gloads) + buf1 A-lo (2) ----
  STAGE(A,  LDA, As0,        m0,       kBase);
  STAGE(A,  LDA, As0 + 8192, m0 + 128, kBase);
  STAGE(Bt, LDB, Bs0,        n0,       kBase);
  STAGE(Bt, LDB, Bs0 + 8192, n0 + 128, kBase);
  STAGE(A,  LDA, As1,        m0,       kBase + 64);
  VMC2;   // buf0 landed; buf1-Alo in flight
  BAR;

  for (int it = 0; it < iters; ++it) {
    const bool nl = (it != iters - 1);
    const int k0t = kBase + it * 128;
    const int kT1 = k0t + 64, kT2 = k0t + 128, kT3 = k0t + 192;

    // ph1: q(0,0) buf0 | reads af-lo, b0, b1 | stage Bs1-lo (T+1)
    read_a<0>(af, As0, wm, rswz);
    read_b<0>(b0, Bs0, wn, rswz);
    read_b<1>(b1, Bs0, wn, rswz);
    STAGE(Bt, LDB, Bs1, n0, kT1);
    mfma16<0,0>(acc, af, b0);
    BAR;
    // ph2: q(0,1) | stage Bs1-hi (T+1)
    STAGE(Bt, LDB, Bs1 + 8192, n0 + 128, kT1);
    mfma16<0,1>(acc, af, b1);
    BAR;
    // ph3: q(1,1) | read af-hi | stage As1-hi (T+1)
    read_a<1>(af, As0, wm, rswz);
    STAGE(A, LDA, As1 + 8192, m0 + 128, kT1);
    mfma16<1,1>(acc, af, b1);
    BAR;
    // ph4: q(1,0) | stage As0-lo (T+2) | VMC: buf1 landed
    if (nl) STAGE(A, LDA, As0, m0, kT2);
    mfma16<1,0>(acc, af, b0);
    if (nl) { VMC2; } else { VMC0; }
    BAR;
    // ph5: q(0,0) buf1 | reads af-lo, b0, b1 | stage Bs0-lo (T+2)
    read_a<0>(af, As1, wm, rswz);
    read_b<0>(b0, Bs1, wn, rswz);
    read_b<1>(b1, Bs1, wn, rswz);
    if (nl) STAGE(Bt, LDB, Bs0, n0, kT2);
    mfma16<0,0>(acc, af, b0);
    BAR;
    // ph6: q(0,1) | stage Bs0-hi (T+2)
    if (nl) STAGE(Bt, LDB, Bs0 + 8192, n0 + 128, kT2);
    mfma16<0,1>(acc, af, b1);
    BAR;
    // ph7: q(1,1) | read af-hi | stage As0-hi (T+2)
    read_a<1>(af, As1, wm, rswz);
    if (nl) STAGE(A, LDA, As0 + 8192, m0 + 128, kT2);
    mfma16<1,1>(acc, af, b1);
    BAR;
    // ph8: q(1,0) | stage As1-lo (T+3) | VMC2: buf0(T+2) landed
    if (nl) STAGE(A, LDA, As1, m0, kT3);
    mfma16<1,0>(acc, af, b0);
    if (nl) { VMC2; }
    BAR;
  }

  // ---- epilogue ----
  const int lr4 = (lane >> 4) * 4;
  const int lc  = lane & 15;
  float gate = 0.f;
  if (EPI == 1) gate = gates[(m0 >> 10) * 8 + (n0 >> 10)];

#pragma unroll
  for (int mi = 0; mi < 8; ++mi) {
    const int rowb = m0 + (mi >> 2) * 128 + wm * 64 + (mi & 3) * 16 + lr4;
#pragma unroll
    for (int nj = 0; nj < 4; ++nj) {
      const int col = n0 + (nj >> 1) * 128 + wn * 32 + (nj & 1) * 16 + lc;
#pragma unroll
      for (int r = 0; r < 4; ++r) {
        const int row = rowb + r;
        float v = acc[mi][nj][r];
        if (EPI == 0) {
          v += bias[col];
          const int which = col >> 10;
          ((unsigned short*)out0)[(long long)which * 4194304 + (long long)row * 1024 + (col & 1023)] = f2bu(v);
        } else if (EPI == 1) {
          v += bias[col];
          float u = 0.7978845608028654f * (v + 0.044715f * v * v * v);
          u = fminf(fmaxf(u, -15.f), 15.f);
          float e2 = __expf(2.f * u);
          float th = (e2 - 1.f) / (e2 + 1.f);
          ((unsigned short*)out0)[(long long)row * 8192 + col] = f2bu(gate * 0.5f * v * (1.f + th));
        } else {
          if (z == 0) ((float*)out0)[(long long)row * 1024 + col] = v;
          else pbs[(long long)(z - 1) * 4194304 + (long long)row * 1024 + col] = f2bu(v);
        }
      }
    }
  }
}

// ---------------------------------------------------------------------------
// out = out + pb0 + pb1 + pb2 (bf16 partials) + bias2[b][n]
// ---------------------------------------------------------------------------
__global__ __launch_bounds__(256)
void reduce3(float* __restrict__ out, const unsigned short* __restrict__ pb,
             const float* __restrict__ bias2)
{
  const int i = (blockIdx.x * 256 + threadIdx.x) * 4;
  const int b = i >> 20;
  const int n = i & 1023;
  float4 a = *(const float4*)(out + i);
  ushort4 p0 = *(const ushort4*)(pb + i);
  ushort4 p1 = *(const ushort4*)(pb + 4194304 + i);
  ushort4 p2 = *(const ushort4*)(pb + 8388608 + i);
  float4 bb = *(const float4*)(bias2 + b * 1024 + n);
  a.x += b2f(p0.x) + b2f(p1.x) + b2f(p2.x) + bb.x;
  a.y += b2f(p0.y) + b2f(p1.y) + b2f(p2.y) + bb.y;
  a.z += b2f(p0.z) + b2f(p1.z) + b2f(p2.z) + bb.z;
  a.w += b2f(p0.w) + b2f(p1.w) + b2f(p2.w) + bb.w;
  *(float4*)(out + i) = a;
}

// ---------------------------------------------------------------------------
// Per-token cross-head attention
// ---------------------------------------------------------------------------
__global__ __launch_bounds__(256)
void attn_kernel(const unsigned short* __restrict__ Qb,
                 const unsigned short* __restrict__ Kb,
                 const unsigned short* __restrict__ Vb,
                 unsigned short* __restrict__ a)
{
  const int token = blockIdx.x;
  const int b = token >> 10, s = token & 1023;
  __shared__ float Qs[16][65], Ks[16][65], Vs[16][65];
  __shared__ float attn_s[16][17];
  const int t = threadIdx.x;
  const long long base = (long long)token * 1024;

  {
    const int i0 = t * 4;
    const int hh = i0 >> 6, dd = i0 & 63;
    ushort4 qv = *(const ushort4*)(Qb + base + i0);
    ushort4 kv = *(const ushort4*)(Kb + base + i0);
    ushort4 vv = *(const ushort4*)(Vb + base + i0);
    Qs[hh][dd+0]=b2f(qv.x); Qs[hh][dd+1]=b2f(qv.y); Qs[hh][dd+2]=b2f(qv.z); Qs[hh][dd+3]=b2f(qv.w);
    Ks[hh][dd+0]=b2f(kv.x); Ks[hh][dd+1]=b2f(kv.y); Ks[hh][dd+2]=b2f(kv.z); Ks[hh][dd+3]=b2f(kv.w);
    Vs[hh][dd+0]=b2f(vv.x); Vs[hh][dd+1]=b2f(vv.y); Vs[hh][dd+2]=b2f(vv.z); Vs[hh][dd+3]=b2f(vv.w);
  }
  __syncthreads();

  const int q = t >> 4, k = t & 15;
  float sc = 0.f;
#pragma unroll
  for (int d = 0; d < 64; ++d) sc += Qs[q][d] * Ks[k][d];
  sc *= 0.125f;
  float mx = sc;
#pragma unroll
  for (int m = 1; m < 16; m <<= 1) mx = fmaxf(mx, __shfl_xor(mx, m, 64));
  float ex = __expf(sc - mx);
  float sum = ex;
#pragma unroll
  for (int m = 1; m < 16; m <<= 1) sum += __shfl_xor(sum, m, 64);
  attn_s[q][k] = ex / sum;
  __syncthreads();

  const int hd = t & 63;
  const int wv = t >> 6;
#pragma unroll
  for (int r = 0; r < 4; ++r) {
    const int qq = wv * 4 + r;
    float o = 0.f;
#pragma unroll
    for (int kk = 0; kk < 16; ++kk) o += attn_s[qq][kk] * Vs[kk][hd];
    a[(long long)b * 1048576 + (long long)(qq * 64 + (s >> 4)) * 1024 + (s & 15) * 64 + hd] = f2bu(o);
  }
}

// ---------------------------------------------------------------------------
// Partial column sums, vectorized ushort4
// ---------------------------------------------------------------------------
__global__ __launch_bounds__(256)
void col_sum_part(const unsigned short* __restrict__ a, float* __restrict__ part)
{
  const int b = blockIdx.x;
  const int y = blockIdx.y;
  const int d4 = threadIdx.x * 4;
  const unsigned short* p = a + (long long)b * 1048576 + (long long)y * 131072 + d4;
  float s0 = 0.f, s1 = 0.f, s2 = 0.f, s3 = 0.f;
  for (int i = 0; i < 128; ++i) {
    ushort4 v = *(const ushort4*)(p + i * 1024);
    s0 += b2f(v.x); s1 += b2f(v.y); s2 += b2f(v.z); s3 += b2f(v.w);
  }
  float* o = part + (y * 4 + b) * 1024 + d4;
  o[0] = s0; o[1] = s1; o[2] = s2; o[3] = s3;
}

__global__ __launch_bounds__(256)
void gates_bias2(const float* __restrict__ part,
                 const float* __restrict__ Wg,
                 const float* __restrict__ bg,
                 const float* __restrict__ b2,
                 float* __restrict__ gates,
                 float* __restrict__ bias2)
{
  __shared__ float am[4][1024];
  __shared__ float sg[4][8];
  const int t = threadIdx.x;

  for (int i = t; i < 4096; i += 256) {
    const int b = i >> 10, d = i & 1023;
    float s = 0.f;
#pragma unroll
    for (int y = 0; y < 8; ++y) s += part[(y * 4 + b) * 1024 + d];
    am[b][d] = s * (1.f / 1024.f);
  }
  __syncthreads();

  const int pair = t >> 3, subl = t & 7;
  const int b = pair >> 3, e = pair & 7;
  float s = 0.f;
  for (int d = subl * 128; d < subl * 128 + 128; ++d) s += am[b][d] * Wg[d * 8 + e];
#pragma unroll
  for (int m = 1; m < 8; m <<= 1) s += __shfl_xor(s, m, 64);
  if (subl == 0) sg[b][e] = s + bg[e];
  __syncthreads();

  if (t < 4) {
    float mx = -1e30f;
    for (int ee = 0; ee < 8; ++ee) mx = fmaxf(mx, sg[t][ee]);
    float g[8]; float ssum = 0.f;
    for (int ee = 0; ee < 8; ++ee) { g[ee] = __expf(sg[t][ee] - mx); ssum += g[ee]; }
    for (int ee = 0; ee < 8; ++ee) { sg[t][ee] = g[ee] / ssum; gates[t * 8 + ee] = sg[t][ee]; }
  }
  __syncthreads();

  for (int i = t; i < 4096; i += 256) {
    const int bb = i >> 10, n = i & 1023;
    float ss = 0.f;
#pragma unroll
    for (int ee = 0; ee < 8; ++ee) ss += sg[bb][ee] * b2[ee * 1024 + n];
    bias2[i] = ss;
  }
}

// ---------------------------------------------------------------------------
// Host launch
// ---------------------------------------------------------------------------
extern "C" void kernel_launch(void* const* d_in, const int* in_sizes, int n_in,
                              void* d_out, int out_size, void* d_ws, size_t ws_size,
                              hipStream_t stream) {
  const float* x  = (const float*)d_in[0];
  const float* Wq = (const float*)d_in[1];
  const float* bq = (const float*)d_in[2];
  const float* Wk = (const float*)d_in[3];
  const float* bk = (const float*)d_in[4];
  const float* Wv = (const float*)d_in[5];
  const float* bv = (const float*)d_in[6];
  const float* Wg = (const float*)d_in[7];
  const float* bg = (const float*)d_in[8];
  const float* W1 = (const float*)d_in[9];
  const float* b1 = (const float*)d_in[10];
  const float* W2 = (const float*)d_in[11];
  const float* b2 = (const float*)d_in[12];
  float* out = (float*)d_out;

  if (ws_size < (size_t)109300000) return;

  char* ws = (char*)d_ws;
  unsigned short* xb   = (unsigned short*)(ws + 0);
  unsigned short* Wqt  = (unsigned short*)(ws + 8388608);     // [3072][1024]
  unsigned short* Qb   = (unsigned short*)(ws + 14680064);    // Q,K,V [3][4096][1024]
  unsigned short* hs   = (unsigned short*)(ws + 0);           // [4096][8192]
  unsigned short* abuf = (unsigned short*)(ws + 67108864);    // [4096][1024]
  unsigned short* pbs  = (unsigned short*)(ws + 67108864);    // 3x[4096][1024] bf16 (after EPI1)
  unsigned short* W1t  = (unsigned short*)(ws + 75497472);    // [8192][1024]
  unsigned short* W2t  = (unsigned short*)(ws + 92274688);    // [1024][8192]
  float* part  = (float*)(ws + 109051904);
  float* gates = (float*)(ws + 109051904 + 131072);
  float* bias2 = (float*)(ws + 109051904 + 131072 + 512);
  float* bqkv  = (float*)(ws + 109051904 + 131072 + 512 + 16384);

  dim3 tb(256);

  transpose_all<<<dim3(16,16,19), tb, 0, stream>>>(Wq, Wk, Wv, W1, W2, Wqt, W1t, W2t);
  cvt_f32_bf16<<<4096, tb, 0, stream>>>(x, xb, 4194304);
  hipMemcpyAsync(bqkv,        bq, 4096, hipMemcpyDeviceToDevice, stream);
  hipMemcpyAsync(bqkv + 1024, bk, 4096, hipMemcpyDeviceToDevice, stream);
  hipMemcpyAsync(bqkv + 2048, bv, 4096, hipMemcpyDeviceToDevice, stream);

  // QKV: M=4096, N=3072 (flat), K=1024
  gemm256<0,1024,1024><<<dim3(12,16,1), 512, 0, stream>>>(xb, Wqt, bqkv,
                                                          Qb, nullptr, 1024, nullptr);
  // Attention -> scrambled a
  attn_kernel<<<4096, tb, 0, stream>>>(Qb, Qb + 4194304, Qb + 8388608, abuf);
  // Gating
  col_sum_part<<<dim3(4,8), tb, 0, stream>>>(abuf, part);
  gates_bias2<<<1, tb, 0, stream>>>(part, Wg, bg, b2, gates, bias2);
  // Expert up-proj + gelu + gate: M=4096, N=8192 (flat experts), K=1024
  gemm256<1,1024,1024><<<dim3(32,16,1), 512, 0, stream>>>(abuf, W1t, b1,
                                                          hs, nullptr, 1024, gates);
  // Final down-proj: M=4096, N=1024, K=8192, split-K 4 (z=0 -> out f32, z>0 -> bf16 partials)
  gemm256<3,8192,8192><<<dim3(4,16,4), 512, 0, stream>>>(hs, W2t, nullptr,
                                                         out, pbs, 2048, nullptr);
  reduce3<<<4096, tb, 0, stream>>>(out, pbs, bias2);
}